// Round 1
// 393.715 us; speedup vs baseline: 1.1055x; 1.1055x over previous
//
#include <hip/hip_runtime.h>
#include <math.h>

namespace {

constexpr int kB = 4;
constexpr int kN = 16384;
constexpr int kS = 4096;
constexpr int kD1 = 128;
constexpr int kD2 = 256;
constexpr int kCO = 256;
constexpr int kNCOL = kB * kN;   // 65536
constexpr int kKX = kD1 + kD2;   // 384, XT row stride

// ws layout (total exactly 67375104 B == known-good bound):
//   pts4  @ 0         float4[16384]          262144 B   {2x,2y,2z,|p|^2}
//   ab0   @ 262144    float[512]
//   ab1   @ 264192    float[512]
//   Y0bf  @ 266240    bf16 [256][65536]      33554432 B
//   X1T   @ 33820672  bf16 [65536][256]      33554432 B  (fea2t fp32 16.8MB overlays here until knn done)
constexpr size_t kOffAb0 = 262144;
constexpr size_t kOffAb1 = 264192;
constexpr size_t kOffY0  = 266240;
constexpr size_t kOffX1  = 33820672;
// out buffer doubles as XT bf16 [65536][384] (50.3MB) until gemm1 writes Y1.

typedef __bf16 bf16x8 __attribute__((ext_vector_type(8)));
typedef float f32x4 __attribute__((ext_vector_type(4)));

__device__ __forceinline__ float bf2f(unsigned short u) {
  unsigned int x = ((unsigned int)u) << 16;
  float f;
  __builtin_memcpy(&f, &x, 4);
  return f;
}
__device__ __forceinline__ unsigned short f2bf(float f) {
  unsigned int x;
  __builtin_memcpy(&x, &f, 4);
  x += 0x7fffu + ((x >> 16) & 1u);  // RNE
  return (unsigned short)(x >> 16);
}

__device__ __forceinline__ void cp16_async(const void* g, void* l) {
#if __has_builtin(__builtin_amdgcn_global_load_lds)
  __builtin_amdgcn_global_load_lds(
      (const __attribute__((address_space(1))) unsigned int*)g,
      (__attribute__((address_space(3))) unsigned int*)l, 16, 0, 0);
#else
  *(uint4*)l = *(const uint4*)g;
#endif
}

// Pack xyz2 into {2x, 2y, 2z, |p|^2}. n2 computed from RAW coords (numpy
// association); doubling xyz is exact (power-of-2), so
// (x*(2px)+y*(2py))+z*(2pz) == 2*((x*px+y*py)+z*pz) bit-for-bit.
__global__ __launch_bounds__(256) void pts4_kernel(const float* __restrict__ xyz2,
                                                   float4* __restrict__ pts4) {
#pragma clang fp contract(off)
  int i = blockIdx.x * 256 + threadIdx.x;
  float x = xyz2[i * 3 + 0];
  float y = xyz2[i * 3 + 1];
  float z = xyz2[i * 3 + 2];
  float4 p;
  p.w = (x * x + y * y) + z * z;
  p.x = x + x; p.y = y + y; p.z = z + z;
  pts4[i] = p;
}

// fea2 [b][c][s] -> fea2t [b][s][c] fp32, 64x64 LDS tiles.
__global__ __launch_bounds__(256) void transpose_kernel(const float* __restrict__ fea2,
                                                        float* __restrict__ fea2t) {
  __shared__ float T[64][65];
  int b = blockIdx.z;
  int c0 = blockIdx.y * 64;
  int s0 = blockIdx.x * 64;
  int t = threadIdx.x;
  {
    int sl = t & 63, cg = t >> 6;
#pragma unroll
    for (int i = 0; i < 16; ++i) {
      int cl = cg * 16 + i;
      T[sl][cl] = fea2[((size_t)(b * kD2 + c0 + cl)) * kS + s0 + sl];
    }
  }
  __syncthreads();
  {
    int cl = t & 63, sg = t >> 6;
#pragma unroll
    for (int i = 0; i < 16; ++i) {
      int sl = sg * 16 + i;
      fea2t[((size_t)(b * kS + s0 + sl)) * kD2 + c0 + cl] = T[sl][cl];
    }
  }
}

// fea1 [b][c][n] fp32 -> XT[j][c] bf16 (cols 0..127), LDS-tiled transpose.
__global__ __launch_bounds__(256) void fea1t_kernel(const float* __restrict__ fea1,
                                                    unsigned short* __restrict__ XT) {
  __shared__ float T[64][129];
  int n0 = blockIdx.x * 64;
  int b = blockIdx.y;
  int t = threadIdx.x;
  {
    int nl = t & 63, cg = t >> 6;  // cg 0..3
#pragma unroll
    for (int i = 0; i < 32; ++i) {
      int c = cg * 32 + i;
      T[nl][c] = fea1[((size_t)(b * kD1 + c)) * kN + n0 + nl];
    }
  }
  __syncthreads();
  {
    int nl = t >> 2, ch = t & 3;  // 32 channels per thread
    unsigned short h[32];
#pragma unroll
    for (int i = 0; i < 32; ++i) h[i] = f2bf(T[nl][ch * 32 + i]);
    uint4* dst = (uint4*)&XT[(size_t)(b * kN + n0 + nl) * kKX + ch * 32];
#pragma unroll
    for (int i = 0; i < 4; ++i) dst[i] = ((uint4*)h)[i];
  }
}

// Block = 512 threads = 64 queries x 8 chunks of 512 points.
// 1024 blocks x 8 waves = 32 waves/CU (was 16): hides the L2-hot point-load
// latency and the gather latency that capped VALUBusy at 55%.
// Inner loop: exact fp32 distance (7 VALU), wave-level ballot skip around the
// top-3 insert. Merge (d,idx)-lexicographic; gather/interp phase uses 8 lanes
// per query so fea2t reads are 128B-contiguous and XT writes are full 64B
// lines (was 16B/8B scatter: 105MB written vs 33.5MB logical).
__global__ __launch_bounds__(512) void knn_interp_kernel(
    const float* __restrict__ xyz1, const float4* __restrict__ pts4,
    const float* __restrict__ fea2t, unsigned short* __restrict__ XT) {
#pragma clang fp contract(off)
  __shared__ float cd[8][64][3];
  __shared__ int ci[8][64][3];
  __shared__ float wsh[3][64];
  __shared__ int ish[3][64];
  int tid = threadIdx.x;
  int q = tid & 63;
  int chunk = __builtin_amdgcn_readfirstlane(tid >> 6);  // 0..7, wave-uniform
  int b = blockIdx.x >> 8;                 // scalar (256 blocks per batch)
  int n0 = (blockIdx.x & 255) * 64;        // scalar
  int n = n0 + q;
  int qg = b * kN + n;

  const float* p1 = xyz1 + (size_t)qg * 3;
  float x = p1[0], y = p1[1], z = p1[2];
  float n1 = (x * x + y * y) + z * z;

  const float4* pp = pts4 + b * kS + chunk * 512;  // scalar base
  int sbase = chunk * 512;
  float d0v = 1e30f, d1v = 1e30f, d2v = 1e30f;
  int i0 = 0, i1 = 0, i2 = 0;
  for (int s = 0; s < 512; s += 4) {
    float4 P[4];
    P[0] = pp[s]; P[1] = pp[s + 1]; P[2] = pp[s + 2]; P[3] = pp[s + 3];
#pragma unroll
    for (int u = 0; u < 4; ++u) {
      float dot2 = (x * P[u].x + y * P[u].y) + z * P[u].z;
      float d = (n1 + P[u].w) - dot2;
      if (__ballot(d < d2v)) {  // wave-uniform skip of the insert
        int si = sbase + s + u;
        bool b0 = d < d0v, b1 = d < d1v, b2 = d < d2v;
        int i2n = b1 ? i1 : (b2 ? si : i2);
        int i1n = b0 ? i0 : (b1 ? si : i1);
        int i0n = b0 ? si : i0;
        d2v = __builtin_amdgcn_fmed3f(d1v, d, d2v);
        d1v = __builtin_amdgcn_fmed3f(d0v, d, d1v);
        d0v = fminf(d0v, d);
        i0 = i0n; i1 = i1n; i2 = i2n;
      }
    }
  }
  cd[chunk][q][0] = d0v; cd[chunk][q][1] = d1v; cd[chunk][q][2] = d2v;
  ci[chunk][q][0] = i0;  ci[chunk][q][1] = i1;  ci[chunk][q][2] = i2;
  __syncthreads();

  if (tid < 64) {
    float D0 = 1e30f, D1 = 1e30f, D2 = 1e30f;
    int I0 = -1, I1 = -1, I2 = -1;
    for (int c2 = 0; c2 < 8; ++c2) {
#pragma unroll
      for (int k = 0; k < 3; ++k) {
        float d = cd[c2][tid][k];
        int i = ci[c2][tid][k];
        bool q0 = (d < D0) || (d == D0 && i < I0);
        bool q1 = (d < D1) || (d == D1 && i < I1);
        bool q2 = (d < D2) || (d == D2 && i < I2);
        if (q0)      { D2 = D1; I2 = I1; D1 = D0; I1 = I0; D0 = d; I0 = i; }
        else if (q1) { D2 = D1; I2 = I1; D1 = d;  I1 = i; }
        else if (q2) { D2 = d;  I2 = i; }
      }
    }
    float r0 = 1.0f / fmaxf(D0, 1e-8f);
    float r1 = 1.0f / fmaxf(D1, 1e-8f);
    float r2 = 1.0f / fmaxf(D2, 1e-8f);
    float rs = (r0 + r1) + r2;
    wsh[0][tid] = r0 / rs; wsh[1][tid] = r1 / rs; wsh[2][tid] = r2 / rs;
    ish[0][tid] = I0; ish[1][tid] = I1; ish[2][tid] = I2;
  }
  __syncthreads();

  // Interp/gather: 8 lanes per query, 64 queries per block (single pass).
  // Lane l covers float4 columns l, l+8, ..., l+56: each 8-lane group reads
  // 128B contiguous per row per step and writes one aligned 64B line.
  int gq = tid >> 3, l = tid & 7;
  float w0 = wsh[0][gq], w1 = wsh[1][gq], w2 = wsh[2][gq];
  int qg2 = b * kN + n0 + gq;
  const float* fb = fea2t + ((size_t)b * kS) * kD2;
  const float* g0p = fb + (size_t)ish[0][gq] * kD2;
  const float* g1p = fb + (size_t)ish[1][gq] * kD2;
  const float* g2p = fb + (size_t)ish[2][gq] * kD2;
  unsigned short* op = XT + (size_t)qg2 * kKX + kD1;  // cols 128..383
#pragma unroll
  for (int k = 0; k < 8; ++k) {
    int c = (l + 8 * k) * 4;  // channel 0..255, step 32 per k
    float4 f0 = *(const float4*)(g0p + c);
    float4 f1 = *(const float4*)(g1p + c);
    float4 f2 = *(const float4*)(g2p + c);
    unsigned short h[4];
    h[0] = f2bf((w0 * f0.x + w1 * f1.x) + w2 * f2.x);
    h[1] = f2bf((w0 * f0.y + w1 * f1.y) + w2 * f2.y);
    h[2] = f2bf((w0 * f0.z + w1 * f1.z) + w2 * f2.z);
    h[3] = f2bf((w0 * f0.w + w1 * f1.w) + w2 * f2.w);
    *(uint2*)(op + c) = *(uint2*)h;
  }
}

// m97-style MFMA GEMM. A = W fp32 [256][KDIM] (cvt->bf16 in staging, L2-hot).
// B = k-major bf16 [65536][KDIM] staged via global_load_lds (16B).
// Tile 128x128, BK=32, 4 waves in 2x2 (64x64 each), 16 mfma/wave/K-step.
// LAYER 0: out bf16 Y0[o][j] + bias. LAYER 1: out fp32 [b][o][n] + bias.
template <int KDIM, int LAYER>
__global__ __launch_bounds__(256) void gemm_kernel(
    const float* __restrict__ W, const unsigned short* __restrict__ Bt,
    const float* __restrict__ bias, void* __restrict__ Yp) {
  constexpr int ALD = 40;                    // padded A stride (ushorts)
  __shared__ unsigned short As[128 * ALD];   // As[m][k]
  __shared__ unsigned short Bs[128 * 32];    // Bs[n][k] contiguous (async dest)
  int tid = threadIdx.x;
  int j0 = blockIdx.x * 128;
  int m0 = blockIdx.y * 128;
  int w = tid >> 6, lane = tid & 63;
  int wm = w & 1, wn = w >> 1;
  int quad = lane >> 4, l16 = lane & 15;
  int arow = tid & 127, ahalf = tid >> 7;    // A: 2x16B per row
  int brow = tid >> 2, bch = tid & 3;        // B: flat 16B chunks

  // runtime C/D layout probe
  bf16x8 pone, pm;
#pragma unroll
  for (int i = 0; i < 8; ++i) { pone[i] = (__bf16)1.0f; pm[i] = (__bf16)(float)l16; }
  f32x4 zf = {};
  f32x4 dr = __builtin_amdgcn_mfma_f32_16x16x32_bf16(pm, pone, zf, 0, 0, 0);
  f32x4 dc = __builtin_amdgcn_mfma_f32_16x16x32_bf16(pone, pm, zf, 0, 0, 0);
  int rowv[4], colv[4];
#pragma unroll
  for (int r = 0; r < 4; ++r) {
    rowv[r] = (int)(dr[r] * (1.0f / 32.0f) + 0.5f);
    colv[r] = (int)(dc[r] * (1.0f / 32.0f) + 0.5f);
  }

  f32x4 acc[4][4] = {};
  for (int k0 = 0; k0 < KDIM; k0 += 32) {
    // B: async 16B direct-to-LDS (wave-uniform base + lane*16 pattern)
    cp16_async(Bt + (size_t)(j0 + brow) * KDIM + k0 + bch * 8, &Bs[(size_t)tid * 8]);
    cp16_async(Bt + (size_t)(j0 + 64 + brow) * KDIM + k0 + bch * 8, &Bs[(size_t)(tid + 256) * 8]);
    // A: fp32 load + cvt + LDS store
    {
      const float* ap = W + (size_t)(m0 + arow) * KDIM + k0 + ahalf * 16;
      float4 f0 = *(const float4*)(ap);
      float4 f1 = *(const float4*)(ap + 4);
      float4 f2 = *(const float4*)(ap + 8);
      float4 f3 = *(const float4*)(ap + 12);
      unsigned short h[16] = {f2bf(f0.x), f2bf(f0.y), f2bf(f0.z), f2bf(f0.w),
                              f2bf(f1.x), f2bf(f1.y), f2bf(f1.z), f2bf(f1.w),
                              f2bf(f2.x), f2bf(f2.y), f2bf(f2.z), f2bf(f2.w),
                              f2bf(f3.x), f2bf(f3.y), f2bf(f3.z), f2bf(f3.w)};
      uint4* dst = (uint4*)&As[arow * ALD + ahalf * 16];
      dst[0] = ((uint4*)h)[0];
      dst[1] = ((uint4*)h)[1];
    }
    __syncthreads();
    bf16x8 af[4], bfr[4];
#pragma unroll
    for (int mt = 0; mt < 4; ++mt)
      af[mt] = *(const bf16x8*)(&As[(wm * 64 + mt * 16 + l16) * ALD + quad * 8]);
#pragma unroll
    for (int nt = 0; nt < 4; ++nt)
      bfr[nt] = *(const bf16x8*)(&Bs[(wn * 64 + nt * 16 + l16) * 32 + quad * 8]);
#pragma unroll
    for (int mt = 0; mt < 4; ++mt)
#pragma unroll
      for (int nt = 0; nt < 4; ++nt)
        acc[mt][nt] = __builtin_amdgcn_mfma_f32_16x16x32_bf16(af[mt], bfr[nt], acc[mt][nt], 0, 0, 0);
    __syncthreads();
  }

#pragma unroll
  for (int mt = 0; mt < 4; ++mt) {
#pragma unroll
    for (int r = 0; r < 4; ++r) {
      int o = m0 + wm * 64 + mt * 16 + rowv[r];
      float bv = bias[o];
#pragma unroll
      for (int nt = 0; nt < 4; ++nt) {
        int j = j0 + wn * 64 + nt * 16 + colv[r];
        float v = acc[mt][nt][r] + bv;
        if (LAYER == 0) {
          ((unsigned short*)Yp)[(size_t)o * kNCOL + j] = f2bf(v);
        } else {
          int bb = j >> 14, nn = j & (kN - 1);
          ((float*)Yp)[((size_t)(bb * kCO + o)) * kN + nn] = v;
        }
      }
    }
  }
}

// Per-channel mean/var of bf16 Y0 [o][65536] -> affine coefs.
__global__ __launch_bounds__(256) void stats0_kernel(const unsigned short* __restrict__ Y,
                                                     const float* __restrict__ gamma,
                                                     const float* __restrict__ beta,
                                                     float* __restrict__ ab) {
  __shared__ float sd[512];
  int o = blockIdx.x, tid = threadIdx.x;
  float s = 0.f, s2 = 0.f;
  const uint4* row = (const uint4*)(Y + (size_t)o * kNCOL);
  for (int v = tid; v < kNCOL / 8; v += 256) {
    uint4 u = row[v];
    const unsigned short* t = (const unsigned short*)&u;
#pragma unroll
    for (int k = 0; k < 8; ++k) { float x = bf2f(t[k]); s += x; s2 += x * x; }
  }
  sd[tid] = s;
  sd[256 + tid] = s2;
  __syncthreads();
  for (int st = 128; st > 0; st >>= 1) {
    if (tid < st) { sd[tid] += sd[tid + st]; sd[256 + tid] += sd[256 + tid + st]; }
    __syncthreads();
  }
  if (tid == 0) {
    float m = sd[0] * (1.0f / 65536.f);
    float var = sd[256] * (1.0f / 65536.f) - m * m;
    float rsq = 1.0f / sqrtf(var + 1e-5f);
    float a = gamma[o] * rsq;
    float c = beta[o] - m * a;
    ab[o] = a;
    ab[kCO + o] = c;
  }
}

// X1T[j][o] = bf16(relu(a[o]*Y0[o][j] + c[o])), tiled transpose.
__global__ __launch_bounds__(256) void apply_kernel(const unsigned short* __restrict__ Y0,
                                                    const float* __restrict__ ab,
                                                    unsigned short* __restrict__ X1T) {
  __shared__ unsigned short T[64][70];
  int j0 = blockIdx.x * 64, o0 = blockIdx.y * 64;
  int t = threadIdx.x;
  {
    int jl = t & 63, og = t >> 6;
#pragma unroll
    for (int i = 0; i < 16; ++i) {
      int ol = og * 16 + i;
      float a = ab[o0 + ol], c = ab[kCO + o0 + ol];
      float v = fmaxf(fmaf(a, bf2f(Y0[(size_t)(o0 + ol) * kNCOL + j0 + jl]), c), 0.f);
      T[ol][jl] = f2bf(v);
    }
  }
  __syncthreads();
  {
    int jl = t >> 2, ch = t & 3;
    unsigned short h[16];
#pragma unroll
    for (int i = 0; i < 16; ++i) h[i] = T[ch * 16 + i][jl];
    uint4* dst = (uint4*)&X1T[(size_t)(j0 + jl) * kCO + o0 + ch * 16];
    dst[0] = ((uint4*)h)[0];
    dst[1] = ((uint4*)h)[1];
  }
}

// fp32 stats over out [b][o][n].
__global__ __launch_bounds__(256) void stats1_kernel(const float* __restrict__ Y,
                                                     const float* __restrict__ gamma,
                                                     const float* __restrict__ beta,
                                                     float* __restrict__ ab) {
  __shared__ float sd[512];
  int o = blockIdx.x, tid = threadIdx.x;
  float s = 0.f, s2 = 0.f;
  for (int bb = 0; bb < kB; ++bb) {
    const float4* row = (const float4*)(Y + ((size_t)(bb * kCO + o)) * kN);
    for (int v = tid; v < kN / 4; v += 256) {
      float4 u = row[v];
      const float* t = (const float*)&u;
#pragma unroll
      for (int k = 0; k < 4; ++k) { float xx = t[k]; s += xx; s2 += xx * xx; }
    }
  }
  sd[tid] = s;
  sd[256 + tid] = s2;
  __syncthreads();
  for (int st = 128; st > 0; st >>= 1) {
    if (tid < st) { sd[tid] += sd[tid + st]; sd[256 + tid] += sd[256 + tid + st]; }
    __syncthreads();
  }
  if (tid == 0) {
    float m = sd[0] * (1.0f / 65536.f);
    float var = sd[256] * (1.0f / 65536.f) - m * m;
    float rsq = 1.0f / sqrtf(var + 1e-5f);
    float a = gamma[o] * rsq;
    float c = beta[o] - m * a;
    ab[o] = a;
    ab[kCO + o] = c;
  }
}

__global__ __launch_bounds__(256) void finalf_kernel(float* __restrict__ Y,
                                                     const float* __restrict__ ab) {
  size_t i = ((size_t)blockIdx.x * 256 + threadIdx.x) * 4;
  int o = (int)((i >> 14) & (kCO - 1));
  float a = ab[o], c = ab[kCO + o];
  float4 u = *(float4*)(Y + i);
  float* t = (float*)&u;
#pragma unroll
  for (int k = 0; k < 4; ++k) t[k] = fmaxf(fmaf(a, t[k], c), 0.0f);
  *(float4*)(Y + i) = u;
}

}  // namespace

extern "C" void kernel_launch(void* const* d_in, const int* in_sizes, int n_in,
                              void* d_out, int out_size, void* d_ws, size_t ws_size,
                              hipStream_t stream) {
  const float* xyz1 = (const float*)d_in[0];
  const float* xyz2 = (const float*)d_in[1];
  const float* fea1 = (const float*)d_in[2];
  const float* fea2 = (const float*)d_in[3];
  const float* W0 = (const float*)d_in[4];
  const float* b0 = (const float*)d_in[5];
  const float* g0 = (const float*)d_in[6];
  const float* be0 = (const float*)d_in[7];
  const float* W1 = (const float*)d_in[8];
  const float* b1 = (const float*)d_in[9];
  const float* g1 = (const float*)d_in[10];
  const float* be1 = (const float*)d_in[11];
  float* out = (float*)d_out;

  char* ws = (char*)d_ws;
  float4* pts4 = (float4*)ws;
  float* ab0 = (float*)(ws + kOffAb0);
  float* ab1 = (float*)(ws + kOffAb1);
  unsigned short* Y0bf = (unsigned short*)(ws + kOffY0);
  unsigned short* X1T = (unsigned short*)(ws + kOffX1);
  float* fea2t = (float*)(ws + kOffX1);            // overlays X1T, dead after knn
  unsigned short* XT = (unsigned short*)d_out;     // bf16 [65536][384], dead after gemm0

  if (ws_size < (size_t)kOffX1 + (size_t)kNCOL * kCO * 2) return;

  pts4_kernel<<<kB * kS / 256, 256, 0, stream>>>(xyz2, pts4);
  transpose_kernel<<<dim3(kS / 64, kD2 / 64, kB), 256, 0, stream>>>(fea2, fea2t);
  fea1t_kernel<<<dim3(kN / 64, kB), 256, 0, stream>>>(fea1, XT);
  knn_interp_kernel<<<kNCOL / 64, 512, 0, stream>>>(xyz1, pts4, fea2t, XT);
  gemm_kernel<kKX, 0><<<dim3(kNCOL / 128, kCO / 128), 256, 0, stream>>>(W0, XT, b0, Y0bf);
  stats0_kernel<<<kCO, 256, 0, stream>>>(Y0bf, g0, be0, ab0);
  apply_kernel<<<dim3(kNCOL / 64, kCO / 64), 256, 0, stream>>>(Y0bf, ab0, X1T);
  gemm_kernel<kCO, 1><<<dim3(kNCOL / 128, kCO / 128), 256, 0, stream>>>(W1, X1T, b1, out);
  stats1_kernel<<<kCO, 256, 0, stream>>>(out, g1, be1, ab1);
  finalf_kernel<<<kCO * kNCOL / (256 * 4), 256, 0, stream>>>(out, ab1);
}